// Round 3
// baseline (129.822 us; speedup 1.0000x reference)
//
#include <hip/hip_runtime.h>
#include <stdint.h>

#define NN 2048

typedef short bf8_t __attribute__((ext_vector_type(8)));   // 8 bf16 (4 VGPRs)
typedef float f32x4 __attribute__((ext_vector_type(4)));

// fp32 -> bf16 RNE, result in TOP 16 bits of return
__device__ __forceinline__ unsigned int rbf(float f) {
    unsigned int u = __builtin_bit_cast(unsigned int, f);
    return u + 0x7FFFu + ((u >> 16) & 1u);
}
__device__ __forceinline__ unsigned short f2b(float f) { return (unsigned short)(rbf(f) >> 16); }
__device__ __forceinline__ unsigned int pk2(float lo, float hi) {
    return (rbf(lo) >> 16) | (rbf(hi) & 0xFFFF0000u);
}

// ---------------------------------------------------------------------------
// prep_kernel (merged so the two independent preps run CONCURRENTLY):
//  blocks 0..511    : per (b, nt): xB = bf16(x/||x||) frag-order, sB = bf16(x@W)
//                     frag-order (support via MFMA, norms in-block)
//  blocks 512..1535 : per (it, mc): amB = bf16(att*mask) in gcn per-lane order
// ---------------------------------------------------------------------------
__global__ __launch_bounds__(256) void prep_kernel(
    const float* __restrict__ x, const float* __restrict__ w,
    const float* __restrict__ att, const int* __restrict__ mask,
    unsigned short* __restrict__ xB, unsigned short* __restrict__ sB,
    unsigned short* __restrict__ amB)
{
    __shared__ unsigned short lds[4 * 64 * 72];
    __shared__ float part[64][4];

    const int t = threadIdx.x;
    const int row = t >> 2, seg = t & 3;
    const int wv = t >> 6, l = t & 63, c = l & 15, q = l >> 4;

    if (blockIdx.x < 512) {
        unsigned short* xs = lds;                // bf16 x tile
        unsigned short* xt = lds + 4608;         // normalized bf16 x tile
        unsigned short* Wt = lds + 9216;         // W^T
        unsigned short* st = lds + 13824;        // support^T
        const int b = blockIdx.x >> 5, nt = blockIdx.x & 31;

        float4 xq[4], wq[4];
        const float* xp = x + ((size_t)(b * NN + nt * 64 + row)) * 64 + seg * 16;
        const float* wp = w + row * 64 + seg * 16;
        #pragma unroll
        for (int i = 0; i < 4; ++i) { xq[i] = ((const float4*)xp)[i]; wq[i] = ((const float4*)wp)[i]; }
        float ss = 0.f;
        #pragma unroll
        for (int i = 0; i < 4; ++i)
            ss += xq[i].x * xq[i].x + xq[i].y * xq[i].y + xq[i].z * xq[i].z + xq[i].w * xq[i].w;
        part[row][seg] = ss;
        #pragma unroll
        for (int i = 0; i < 4; ++i) {
            ((unsigned int*)&xs[row * 72 + seg * 16])[i * 2]     = pk2(xq[i].x, xq[i].y);
            ((unsigned int*)&xs[row * 72 + seg * 16])[i * 2 + 1] = pk2(xq[i].z, xq[i].w);
            Wt[(seg * 16 + i * 4 + 0) * 72 + row] = f2b(wq[i].x);
            Wt[(seg * 16 + i * 4 + 1) * 72 + row] = f2b(wq[i].y);
            Wt[(seg * 16 + i * 4 + 2) * 72 + row] = f2b(wq[i].z);
            Wt[(seg * 16 + i * 4 + 3) * 72 + row] = f2b(wq[i].w);
        }
        __syncthreads();

        const float rinv = 1.0f / sqrtf(part[row][0] + part[row][1] + part[row][2] + part[row][3]);
        #pragma unroll
        for (int i = 0; i < 4; ++i) {
            ((unsigned int*)&xt[row * 72 + seg * 16])[i * 2]     = pk2(xq[i].x * rinv, xq[i].y * rinv);
            ((unsigned int*)&xt[row * 72 + seg * 16])[i * 2 + 1] = pk2(xq[i].z * rinv, xq[i].w * rinv);
        }
        __syncthreads();

        {   // xB frag store (cb = wv)
            bf8_t h0 = *(const bf8_t*)&xt[(wv * 16 + c) * 72 + q * 8];
            bf8_t h1 = *(const bf8_t*)&xt[(wv * 16 + c) * 72 + 32 + q * 8];
            unsigned short* base = xB + ((size_t)(b * 32 + nt)) * 4096 + wv * 1024 + l * 8;
            *(bf8_t*)base = h0;
            *(bf8_t*)(base + 512) = h1;
        }
        {   // support rows wv*16..+15: S = x @ W  (MFMA), scatter to st (e-major)
            bf8_t a0 = *(const bf8_t*)&xs[(wv * 16 + c) * 72 + q * 8];
            bf8_t a1 = *(const bf8_t*)&xs[(wv * 16 + c) * 72 + 32 + q * 8];
            #pragma unroll
            for (int cb = 0; cb < 4; ++cb) {
                bf8_t b0 = *(const bf8_t*)&Wt[(cb * 16 + c) * 72 + q * 8];
                bf8_t b1 = *(const bf8_t*)&Wt[(cb * 16 + c) * 72 + 32 + q * 8];
                f32x4 z = (f32x4){0.f, 0.f, 0.f, 0.f};
                z = __builtin_amdgcn_mfma_f32_16x16x32_bf16(a0, b0, z, 0, 0, 0);
                z = __builtin_amdgcn_mfma_f32_16x16x32_bf16(a1, b1, z, 0, 0, 0);
                #pragma unroll
                for (int r = 0; r < 4; ++r)
                    st[(cb * 16 + c) * 72 + wv * 16 + q * 4 + r] = f2b(z[r]);
            }
        }
        __syncthreads();
        {   // sB frag store
            bf8_t h0 = *(const bf8_t*)&st[(wv * 16 + c) * 72 + q * 8];
            bf8_t h1 = *(const bf8_t*)&st[(wv * 16 + c) * 72 + 32 + q * 8];
            unsigned short* base = sB + ((size_t)(b * 32 + nt)) * 4096 + wv * 1024 + l * 8;
            *(bf8_t*)base = h0;
            *(bf8_t*)(base + 512) = h1;
        }
    } else {
        unsigned short* amt = lds;
        const int bid = blockIdx.x - 512;
        const int it = bid >> 5, mc = bid & 31;
        const size_t g = ((size_t)(it * 64 + row)) * NN + mc * 64 + seg * 16;
        #pragma unroll
        for (int i = 0; i < 4; ++i) {
            float4 a = *(const float4*)(att + g + i * 4);
            int4   m = *(const int4*)(mask + g + i * 4);
            ((unsigned int*)&amt[row * 72 + seg * 16])[i * 2] =
                pk2(a.x * (float)m.x, a.y * (float)m.y);
            ((unsigned int*)&amt[row * 72 + seg * 16])[i * 2 + 1] =
                pk2(a.z * (float)m.z, a.w * (float)m.w);
        }
        __syncthreads();
        unsigned int ww[8];
        #pragma unroll
        for (int rbi = 0; rbi < 4; ++rbi) {
            #pragma unroll
            for (int rp = 0; rp < 2; ++rp) {
                unsigned int lo = amt[(rbi * 16 + c) * 72 + wv * 16 + q * 4 + rp * 2];
                unsigned int hi = amt[(rbi * 16 + c) * 72 + wv * 16 + q * 4 + rp * 2 + 1];
                ww[rbi * 2 + rp] = lo | (hi << 16);
            }
        }
        unsigned short* base = amB + ((size_t)(it * 32 + mc)) * 4096 + wv * 1024 + l * 8;
        *(uint4*)base         = *(uint4*)&ww[0];
        *(uint4*)(base + 512) = *(uint4*)&ww[4];
    }
}

// ---------------------------------------------------------------------------
// gcn_kernel: block = (b, it, half); wave wm owns 64 i-rows x mc in
// {half*16 + wm + 4*tt, tt=0..3}. No barriers in the loop (all operands are
// coalesced frag-order global loads; Adj is wave-private LDS).
// launch_bounds(256,3): cap VGPR ~170 -> 3 blocks/CU (12 waves) vs 2 before.
// Epilogue: 4-wave LDS reduction -> fp32 partial tile to ws (reduce_kernel
// folds the two halves + bias).
// ---------------------------------------------------------------------------
__global__ __launch_bounds__(256, 3) void gcn_kernel(
    const unsigned short* __restrict__ xB, const unsigned short* __restrict__ sB,
    const unsigned short* __restrict__ amB, float* __restrict__ pout)
{
    __shared__ unsigned short Adj[4][64 * 72];   // 36,864 B; reused as fp32 red
    const int t = threadIdx.x;
    const int wm = t >> 6, l = t & 63, c = l & 15, q = l >> 4;
    const int blk = blockIdx.x;
    const int half = blk & 1, it = (blk >> 1) & 31, b = blk >> 6;

    const unsigned short* xit = xB + ((size_t)(b * 32 + it)) * 4096;
    bf8_t xi0[4], xi1[4];
    #pragma unroll
    for (int rb = 0; rb < 4; ++rb) {
        xi0[rb] = *(const bf8_t*)(xit + rb * 1024 + l * 8);
        xi1[rb] = *(const bf8_t*)(xit + rb * 1024 + 512 + l * 8);
    }
    f32x4 acc[4][4];
    #pragma unroll
    for (int rb = 0; rb < 4; ++rb)
        #pragma unroll
        for (int cb = 0; cb < 4; ++cb) acc[rb][cb] = (f32x4){0.f, 0.f, 0.f, 0.f};

    unsigned short* adj = &Adj[wm][0];

    for (int tt = 0; tt < 4; ++tt) {
        const int mc = half * 16 + wm + tt * 4;
        const unsigned short* xmt = xB + ((size_t)(b * 32 + mc)) * 4096;
        const unsigned short* smt = sB + ((size_t)(b * 32 + mc)) * 4096;
        const unsigned short* amp = amB + ((size_t)(it * 32 + mc)) * 4096;
        bf8_t xm0[4], xm1[4], sm0[4], sm1[4];
        uint4 amv[8];
        #pragma unroll
        for (int cb = 0; cb < 4; ++cb) {
            xm0[cb] = *(const bf8_t*)(xmt + cb * 1024 + l * 8);
            xm1[cb] = *(const bf8_t*)(xmt + cb * 1024 + 512 + l * 8);
        }
        #pragma unroll
        for (int j = 0; j < 8; ++j) amv[j] = *(const uint4*)(amp + j * 512 + l * 8);

        // GEMM1: mup^T tile (m rows, i cols); norms pre-folded into xB
        #pragma unroll
        for (int cbm = 0; cbm < 4; ++cbm) {
            #pragma unroll
            for (int rbi = 0; rbi < 4; ++rbi) {
                f32x4 z = (f32x4){0.f, 0.f, 0.f, 0.f};
                z = __builtin_amdgcn_mfma_f32_16x16x32_bf16(xm0[cbm], xi0[rbi], z, 0, 0, 0);
                z = __builtin_amdgcn_mfma_f32_16x16x32_bf16(xm1[cbm], xi1[rbi], z, 0, 0, 0);
                const unsigned int w0 = ((const unsigned int*)&amv[cbm * 2 + (rbi >> 1)])[(rbi & 1) * 2 + 0];
                const unsigned int w1 = ((const unsigned int*)&amv[cbm * 2 + (rbi >> 1)])[(rbi & 1) * 2 + 1];
                const float a0f = __builtin_bit_cast(float, w0 << 16);
                const float a1f = __builtin_bit_cast(float, w0 & 0xFFFF0000u);
                const float a2f = __builtin_bit_cast(float, w1 << 16);
                const float a3f = __builtin_bit_cast(float, w1 & 0xFFFF0000u);
                uint2 p;
                p.x = pk2(z[0] * a0f, z[1] * a1f);
                p.y = pk2(z[2] * a2f, z[3] * a3f);
                *(uint2*)&adj[(rbi * 16 + c) * 72 + cbm * 16 + q * 4] = p;
            }
        }
        #pragma unroll
        for (int cb = 0; cb < 4; ++cb) {
            sm0[cb] = *(const bf8_t*)(smt + cb * 1024 + l * 8);
            sm1[cb] = *(const bf8_t*)(smt + cb * 1024 + 512 + l * 8);
        }
        // GEMM2: out += Adj @ S  (A-frags from wave-private Adj; same-wave order)
        #pragma unroll
        for (int rb = 0; rb < 4; ++rb) {
            bf8_t p0 = *(const bf8_t*)&adj[(rb * 16 + c) * 72 + q * 8];
            bf8_t p1 = *(const bf8_t*)&adj[(rb * 16 + c) * 72 + 32 + q * 8];
            #pragma unroll
            for (int cb = 0; cb < 4; ++cb) {
                acc[rb][cb] = __builtin_amdgcn_mfma_f32_16x16x32_bf16(p0, sm0[cb], acc[rb][cb], 0, 0, 0);
                acc[rb][cb] = __builtin_amdgcn_mfma_f32_16x16x32_bf16(p1, sm1[cb], acc[rb][cb], 0, 0, 0);
            }
        }
    }

    // epilogue: cross-wave reduction -> fp32 partial tile (64x64) to ws
    float* red = (float*)&Adj[0][0];             // 4 regions x 2176 floats (stride 68)
    float* pw = pout + (size_t)blk * 4096;
    for (int h = 0; h < 2; ++h) {
        __syncthreads();
        #pragma unroll
        for (int rb2 = 0; rb2 < 2; ++rb2) {
            const int rb = h * 2 + rb2;
            #pragma unroll
            for (int cb = 0; cb < 4; ++cb)
                #pragma unroll
                for (int r = 0; r < 4; ++r)
                    red[wm * 2176 + (rb2 * 16 + q * 4 + r) * 68 + cb * 16 + c] = acc[rb][cb][r];
        }
        __syncthreads();
        #pragma unroll
        for (int rnd = 0; rnd < 8; ++rnd) {
            const int idx = rnd * 256 + t;
            const int row = idx >> 6, col = idx & 63;
            pw[(h * 32 + row) * 64 + col] =
                  red[0 * 2176 + row * 68 + col] + red[1 * 2176 + row * 68 + col]
                + red[2 * 2176 + row * 68 + col] + red[3 * 2176 + row * 68 + col];
        }
    }
}

// ---------------------------------------------------------------------------
// reduce_kernel: out = p[half0] + p[half1] + bias (float4, fully coalesced)
// out flat j: tile = j>>12 (= b*32+it), off = j&4095; partials at tile*2(+1).
// ---------------------------------------------------------------------------
__global__ __launch_bounds__(256) void reduce_kernel(
    const float* __restrict__ p, const float* __restrict__ bias,
    float* __restrict__ out)
{
    const int j = (blockIdx.x * 256 + threadIdx.x) * 4;
    const int tile = j >> 12, off = j & 4095;
    const float4 a  = *(const float4*)(p + (size_t)tile * 8192 + off);
    const float4 bq = *(const float4*)(p + (size_t)tile * 8192 + 4096 + off);
    const float4 bs = *(const float4*)(bias + (j & 63));
    float4 o;
    o.x = a.x + bq.x + bs.x;
    o.y = a.y + bq.y + bs.y;
    o.z = a.z + bq.z + bs.z;
    o.w = a.w + bq.w + bs.w;
    *(float4*)(out + j) = o;
}

extern "C" void kernel_launch(void* const* d_in, const int* in_sizes, int n_in,
                              void* d_out, int out_size, void* d_ws, size_t ws_size,
                              hipStream_t stream) {
    const float* x    = (const float*)d_in[0];   // [16,2048,64]
    const float* w    = (const float*)d_in[1];   // [64,64]
    const float* att  = (const float*)d_in[2];   // [2048,2048]
    const float* bias = (const float*)d_in[3];   // [64]
    const int*   mask = (const int*)d_in[4];     // [2048,2048]
    float* out = (float*)d_out;                  // [16,2048,64]

    // ws: xB 4 MB | sB 4 MB | amB 8 MB | partials 16 MB
    unsigned short* xB  = (unsigned short*)d_ws;
    unsigned short* sB  = xB + (size_t)2 * 1024 * 1024;
    unsigned short* amB = sB + (size_t)2 * 1024 * 1024;
    float* pout = (float*)(amB + (size_t)4 * 1024 * 1024);

    prep_kernel<<<dim3(1536), dim3(256), 0, stream>>>(x, w, att, mask, xB, sB, amB);
    gcn_kernel<<<dim3(1024), dim3(256), 0, stream>>>(xB, sB, amB, pout);
    reduce_kernel<<<dim3(2048), dim3(256), 0, stream>>>(pout, bias, out);
}

// Round 4
// 115.229 us; speedup vs baseline: 1.1266x; 1.1266x over previous
//
#include <hip/hip_runtime.h>
#include <stdint.h>

#define NN 2048

typedef short bf8_t __attribute__((ext_vector_type(8)));   // 8 bf16 (4 VGPRs)
typedef float f32x4 __attribute__((ext_vector_type(4)));

// fp32 -> bf16 RNE, result in TOP 16 bits of return
__device__ __forceinline__ unsigned int rbf(float f) {
    unsigned int u = __builtin_bit_cast(unsigned int, f);
    return u + 0x7FFFu + ((u >> 16) & 1u);
}
__device__ __forceinline__ unsigned short f2b(float f) { return (unsigned short)(rbf(f) >> 16); }
__device__ __forceinline__ unsigned int pk2(float lo, float hi) {
    return (rbf(lo) >> 16) | (rbf(hi) & 0xFFFF0000u);
}

// ---------------------------------------------------------------------------
// prep_kernel (merged; the two independent preps run concurrently):
//  blocks 0..511    : per (b, nt): xB = bf16(x/||x||) frag-order, sB = bf16(x@W)
//  blocks 512..1535 : per (it, mc): amB = bf16(att*mask) in gcn per-lane order
// ---------------------------------------------------------------------------
__global__ __launch_bounds__(256) void prep_kernel(
    const float* __restrict__ x, const float* __restrict__ w,
    const float* __restrict__ att, const int* __restrict__ mask,
    unsigned short* __restrict__ xB, unsigned short* __restrict__ sB,
    unsigned short* __restrict__ amB)
{
    __shared__ unsigned short lds[4 * 64 * 72];
    __shared__ float part[64][4];

    const int t = threadIdx.x;
    const int row = t >> 2, seg = t & 3;
    const int wv = t >> 6, l = t & 63, c = l & 15, q = l >> 4;

    if (blockIdx.x < 512) {
        unsigned short* xs = lds;                // bf16 x tile
        unsigned short* xt = lds + 4608;         // normalized bf16 x tile
        unsigned short* Wt = lds + 9216;         // W^T
        unsigned short* st = lds + 13824;        // support^T
        const int b = blockIdx.x >> 5, nt = blockIdx.x & 31;

        float4 xq[4], wq[4];
        const float* xp = x + ((size_t)(b * NN + nt * 64 + row)) * 64 + seg * 16;
        const float* wp = w + row * 64 + seg * 16;
        #pragma unroll
        for (int i = 0; i < 4; ++i) { xq[i] = ((const float4*)xp)[i]; wq[i] = ((const float4*)wp)[i]; }
        float ss = 0.f;
        #pragma unroll
        for (int i = 0; i < 4; ++i)
            ss += xq[i].x * xq[i].x + xq[i].y * xq[i].y + xq[i].z * xq[i].z + xq[i].w * xq[i].w;
        part[row][seg] = ss;
        #pragma unroll
        for (int i = 0; i < 4; ++i) {
            ((unsigned int*)&xs[row * 72 + seg * 16])[i * 2]     = pk2(xq[i].x, xq[i].y);
            ((unsigned int*)&xs[row * 72 + seg * 16])[i * 2 + 1] = pk2(xq[i].z, xq[i].w);
            Wt[(seg * 16 + i * 4 + 0) * 72 + row] = f2b(wq[i].x);
            Wt[(seg * 16 + i * 4 + 1) * 72 + row] = f2b(wq[i].y);
            Wt[(seg * 16 + i * 4 + 2) * 72 + row] = f2b(wq[i].z);
            Wt[(seg * 16 + i * 4 + 3) * 72 + row] = f2b(wq[i].w);
        }
        __syncthreads();

        const float rinv = 1.0f / sqrtf(part[row][0] + part[row][1] + part[row][2] + part[row][3]);
        #pragma unroll
        for (int i = 0; i < 4; ++i) {
            ((unsigned int*)&xt[row * 72 + seg * 16])[i * 2]     = pk2(xq[i].x * rinv, xq[i].y * rinv);
            ((unsigned int*)&xt[row * 72 + seg * 16])[i * 2 + 1] = pk2(xq[i].z * rinv, xq[i].w * rinv);
        }
        __syncthreads();

        {   // xB frag store (cb = wv)
            bf8_t h0 = *(const bf8_t*)&xt[(wv * 16 + c) * 72 + q * 8];
            bf8_t h1 = *(const bf8_t*)&xt[(wv * 16 + c) * 72 + 32 + q * 8];
            unsigned short* base = xB + ((size_t)(b * 32 + nt)) * 4096 + wv * 1024 + l * 8;
            *(bf8_t*)base = h0;
            *(bf8_t*)(base + 512) = h1;
        }
        {   // support rows wv*16..+15: S = x @ W (MFMA), scatter to st (e-major)
            bf8_t a0 = *(const bf8_t*)&xs[(wv * 16 + c) * 72 + q * 8];
            bf8_t a1 = *(const bf8_t*)&xs[(wv * 16 + c) * 72 + 32 + q * 8];
            #pragma unroll
            for (int cb = 0; cb < 4; ++cb) {
                bf8_t b0 = *(const bf8_t*)&Wt[(cb * 16 + c) * 72 + q * 8];
                bf8_t b1 = *(const bf8_t*)&Wt[(cb * 16 + c) * 72 + 32 + q * 8];
                f32x4 z = (f32x4){0.f, 0.f, 0.f, 0.f};
                z = __builtin_amdgcn_mfma_f32_16x16x32_bf16(a0, b0, z, 0, 0, 0);
                z = __builtin_amdgcn_mfma_f32_16x16x32_bf16(a1, b1, z, 0, 0, 0);
                #pragma unroll
                for (int r = 0; r < 4; ++r)
                    st[(cb * 16 + c) * 72 + wv * 16 + q * 4 + r] = f2b(z[r]);
            }
        }
        __syncthreads();
        {   // sB frag store
            bf8_t h0 = *(const bf8_t*)&st[(wv * 16 + c) * 72 + q * 8];
            bf8_t h1 = *(const bf8_t*)&st[(wv * 16 + c) * 72 + 32 + q * 8];
            unsigned short* base = sB + ((size_t)(b * 32 + nt)) * 4096 + wv * 1024 + l * 8;
            *(bf8_t*)base = h0;
            *(bf8_t*)(base + 512) = h1;
        }
    } else {
        unsigned short* amt = lds;
        const int bid = blockIdx.x - 512;
        const int it = bid >> 5, mc = bid & 31;
        const size_t g = ((size_t)(it * 64 + row)) * NN + mc * 64 + seg * 16;
        #pragma unroll
        for (int i = 0; i < 4; ++i) {
            float4 a = *(const float4*)(att + g + i * 4);
            int4   m = *(const int4*)(mask + g + i * 4);
            ((unsigned int*)&amt[row * 72 + seg * 16])[i * 2] =
                pk2(a.x * (float)m.x, a.y * (float)m.y);
            ((unsigned int*)&amt[row * 72 + seg * 16])[i * 2 + 1] =
                pk2(a.z * (float)m.z, a.w * (float)m.w);
        }
        __syncthreads();
        unsigned int ww[8];
        #pragma unroll
        for (int rbi = 0; rbi < 4; ++rbi) {
            #pragma unroll
            for (int rp = 0; rp < 2; ++rp) {
                unsigned int lo = amt[(rbi * 16 + c) * 72 + wv * 16 + q * 4 + rp * 2];
                unsigned int hi = amt[(rbi * 16 + c) * 72 + wv * 16 + q * 4 + rp * 2 + 1];
                ww[rbi * 2 + rp] = lo | (hi << 16);
            }
        }
        unsigned short* base = amB + ((size_t)(it * 32 + mc)) * 4096 + wv * 1024 + l * 8;
        *(uint4*)base         = *(uint4*)&ww[0];
        *(uint4*)(base + 512) = *(uint4*)&ww[4];
    }
}

// ---------------------------------------------------------------------------
// gcn_kernel: block = (b, it) with XCD swizzle: it = (bid&7)*4 + ((bid>>3)&3)
// so XCD x (= bid%8 round-robin heuristic) serves it in {4x..4x+3} for ALL
// batches -> its amB slice (1 MB) stays L2-resident across the 16 batches.
// Wave wm owns all 64 i-rows x mc in {wm+4tt}. No barriers in the loop.
// Explicit double-buffered xm prefetch: next iter's GEMM1 head operand loads
// during current pack+GEMM2 (ILP, not TLP — R3 showed TLP doesn't help).
// ---------------------------------------------------------------------------
__global__ __launch_bounds__(256, 2) void gcn_kernel(
    const unsigned short* __restrict__ xB, const unsigned short* __restrict__ sB,
    const unsigned short* __restrict__ amB, const float* __restrict__ bias,
    float* __restrict__ out)
{
    __shared__ unsigned short Adj[4][64 * 72];   // 36,864 B; reused as fp32 red
    const int t = threadIdx.x;
    const int wm = t >> 6, l = t & 63, c = l & 15, q = l >> 4;
    const int bid = blockIdx.x;
    const int r8 = bid & 31, b = bid >> 5;
    const int it = (r8 & 7) * 4 + (r8 >> 3);     // XCD-pinned it-group

    const unsigned short* xit = xB + ((size_t)(b * 32 + it)) * 4096;
    bf8_t xi0[4], xi1[4];
    #pragma unroll
    for (int rb = 0; rb < 4; ++rb) {
        xi0[rb] = *(const bf8_t*)(xit + rb * 1024 + l * 8);
        xi1[rb] = *(const bf8_t*)(xit + rb * 1024 + 512 + l * 8);
    }
    f32x4 acc[4][4];
    #pragma unroll
    for (int rb = 0; rb < 4; ++rb)
        #pragma unroll
        for (int cb = 0; cb < 4; ++cb) acc[rb][cb] = (f32x4){0.f, 0.f, 0.f, 0.f};

    unsigned short* adj = &Adj[wm][0];

    // prefetch buffers (double-buffered xm; am single-buffered: consumed late
    // enough that a loop-top load covers L2-hit latency after the swizzle)
    bf8_t xmA0[4], xmA1[4], xmB0[4], xmB1[4];
    {
        const unsigned short* xmt = xB + ((size_t)(b * 32 + wm)) * 4096;
        #pragma unroll
        for (int cb = 0; cb < 4; ++cb) {
            xmA0[cb] = *(const bf8_t*)(xmt + cb * 1024 + l * 8);
            xmA1[cb] = *(const bf8_t*)(xmt + cb * 1024 + 512 + l * 8);
        }
    }

    #pragma unroll
    for (int tt = 0; tt < 8; ++tt) {
        const int mc = wm + tt * 4;
        const unsigned short* smt = sB + ((size_t)(b * 32 + mc)) * 4096;
        const unsigned short* amp = amB + ((size_t)(it * 32 + mc)) * 4096;
        bf8_t sm0[4], sm1[4];
        uint4 amv[8];
        #pragma unroll
        for (int j = 0; j < 8; ++j) amv[j] = *(const uint4*)(amp + j * 512 + l * 8);
        #pragma unroll
        for (int cb = 0; cb < 4; ++cb) {
            sm0[cb] = *(const bf8_t*)(smt + cb * 1024 + l * 8);
            sm1[cb] = *(const bf8_t*)(smt + cb * 1024 + 512 + l * 8);
        }
        // prefetch next xm into the other buffer
        if (tt < 7) {
            const unsigned short* xmn = xB + ((size_t)(b * 32 + mc + 4)) * 4096;
            if ((tt & 1) == 0) {
                #pragma unroll
                for (int cb = 0; cb < 4; ++cb) {
                    xmB0[cb] = *(const bf8_t*)(xmn + cb * 1024 + l * 8);
                    xmB1[cb] = *(const bf8_t*)(xmn + cb * 1024 + 512 + l * 8);
                }
            } else {
                #pragma unroll
                for (int cb = 0; cb < 4; ++cb) {
                    xmA0[cb] = *(const bf8_t*)(xmn + cb * 1024 + l * 8);
                    xmA1[cb] = *(const bf8_t*)(xmn + cb * 1024 + 512 + l * 8);
                }
            }
        }
        const bf8_t* xm0 = (tt & 1) ? xmB0 : xmA0;
        const bf8_t* xm1 = (tt & 1) ? xmB1 : xmA1;

        // GEMM1: mup^T tile (m rows, i cols); norms pre-folded into xB
        #pragma unroll
        for (int cbm = 0; cbm < 4; ++cbm) {
            #pragma unroll
            for (int rbi = 0; rbi < 4; ++rbi) {
                f32x4 z = (f32x4){0.f, 0.f, 0.f, 0.f};
                z = __builtin_amdgcn_mfma_f32_16x16x32_bf16(xm0[cbm], xi0[rbi], z, 0, 0, 0);
                z = __builtin_amdgcn_mfma_f32_16x16x32_bf16(xm1[cbm], xi1[rbi], z, 0, 0, 0);
                const unsigned int w0 = ((const unsigned int*)&amv[cbm * 2 + (rbi >> 1)])[(rbi & 1) * 2 + 0];
                const unsigned int w1 = ((const unsigned int*)&amv[cbm * 2 + (rbi >> 1)])[(rbi & 1) * 2 + 1];
                const float a0f = __builtin_bit_cast(float, w0 << 16);
                const float a1f = __builtin_bit_cast(float, w0 & 0xFFFF0000u);
                const float a2f = __builtin_bit_cast(float, w1 << 16);
                const float a3f = __builtin_bit_cast(float, w1 & 0xFFFF0000u);
                uint2 p;
                p.x = pk2(z[0] * a0f, z[1] * a1f);
                p.y = pk2(z[2] * a2f, z[3] * a3f);
                *(uint2*)&adj[(rbi * 16 + c) * 72 + cbm * 16 + q * 4] = p;
            }
        }
        // GEMM2: out += Adj @ S (A-frags from wave-private Adj; same-wave order)
        #pragma unroll
        for (int rb = 0; rb < 4; ++rb) {
            bf8_t p0 = *(const bf8_t*)&adj[(rb * 16 + c) * 72 + q * 8];
            bf8_t p1 = *(const bf8_t*)&adj[(rb * 16 + c) * 72 + 32 + q * 8];
            #pragma unroll
            for (int cb = 0; cb < 4; ++cb) {
                acc[rb][cb] = __builtin_amdgcn_mfma_f32_16x16x32_bf16(p0, sm0[cb], acc[rb][cb], 0, 0, 0);
                acc[rb][cb] = __builtin_amdgcn_mfma_f32_16x16x32_bf16(p1, sm1[cb], acc[rb][cb], 0, 0, 0);
            }
        }
    }

    // epilogue: cross-wave reduction (LDS reused as fp32), direct store + bias
    float* red = (float*)&Adj[0][0];             // 4 regions x 2176 floats (stride 68)
    const int i0 = it * 64;
    for (int h = 0; h < 2; ++h) {
        __syncthreads();
        #pragma unroll
        for (int rb2 = 0; rb2 < 2; ++rb2) {
            const int rb = h * 2 + rb2;
            #pragma unroll
            for (int cb = 0; cb < 4; ++cb)
                #pragma unroll
                for (int r = 0; r < 4; ++r)
                    red[wm * 2176 + (rb2 * 16 + q * 4 + r) * 68 + cb * 16 + c] = acc[rb][cb][r];
        }
        __syncthreads();
        #pragma unroll
        for (int rnd = 0; rnd < 8; ++rnd) {
            const int idx = rnd * 256 + t;
            const int row = idx >> 6, col = idx & 63;
            const float s = red[0 * 2176 + row * 68 + col] + red[1 * 2176 + row * 68 + col]
                          + red[2 * 2176 + row * 68 + col] + red[3 * 2176 + row * 68 + col];
            out[((size_t)(b * NN + i0 + h * 32 + row)) * 64 + col] = s + bias[col];
        }
    }
}

extern "C" void kernel_launch(void* const* d_in, const int* in_sizes, int n_in,
                              void* d_out, int out_size, void* d_ws, size_t ws_size,
                              hipStream_t stream) {
    const float* x    = (const float*)d_in[0];   // [16,2048,64]
    const float* w    = (const float*)d_in[1];   // [64,64]
    const float* att  = (const float*)d_in[2];   // [2048,2048]
    const float* bias = (const float*)d_in[3];   // [64]
    const int*   mask = (const int*)d_in[4];     // [2048,2048]
    float* out = (float*)d_out;                  // [16,2048,64]

    // ws: xB 4 MB | sB 4 MB | amB 8 MB
    unsigned short* xB  = (unsigned short*)d_ws;
    unsigned short* sB  = xB + (size_t)2 * 1024 * 1024;
    unsigned short* amB = sB + (size_t)2 * 1024 * 1024;

    prep_kernel<<<dim3(1536), dim3(256), 0, stream>>>(x, w, att, mask, xB, sB, amB);
    gcn_kernel<<<dim3(512), dim3(256), 0, stream>>>(xB, sB, amB, bias, out);
}